// Round 5
// baseline (8628.869 us; speedup 1.0000x reference)
//
#include <hip/hip_runtime.h>
#include <hip/hip_bf16.h>

#define BB 32
#define TT 64
#define NNODE 1024
#define EE 4096
#define NEDGE 5120        // EE + NNODE self loops
#define NHEAD 8
#define HLL 512
#define HRR 64
#define TWO_N 2048
#define KCELL 2560        // 2048 (xf) + 512 (hn)

__device__ __forceinline__ float sigmoidf_(float x){ return 1.f/(1.f+expf(-x)); }
__device__ __forceinline__ float leaky(float x, float s){ return x>0.f? x : s*x; }

// ---------------- LSTM over T steps, one block per batch ----------------
__global__ __launch_bounds__(256) void k_lstm(
    const float* __restrict__ rain, const float* __restrict__ Wih,
    const float* __restrict__ Whh, const float* __restrict__ bih,
    const float* __restrict__ bhh, float* __restrict__ hs){
  int b = blockIdx.x;
  int j = threadIdx.x;          // gate row 0..255
  __shared__ float h_lds[HRR];
  __shared__ float g_lds[4*HRR];
  float wh[HRR];
  #pragma unroll
  for(int k=0;k<HRR;k++) wh[k] = Whh[j*HRR+k];
  float wi = Wih[j];
  float bias = bih[j] + bhh[j];
  float c = 0.f;
  if(j < HRR) h_lds[j] = 0.f;
  __syncthreads();
  for(int t=0;t<TT;t++){
    float x = rain[b*TT+t];
    float g = fmaf(wi, x, bias);
    #pragma unroll
    for(int k=0;k<HRR;k++) g = fmaf(wh[k], h_lds[k], g);
    g_lds[j] = g;
    __syncthreads();
    if(j < HRR){
      c = sigmoidf_(g_lds[HRR+j])*c + sigmoidf_(g_lds[j])*tanhf(g_lds[2*HRR+j]);
      float h = sigmoidf_(g_lds[3*HRR+j])*tanhf(c);
      h_lds[j] = h;
      hs[(t*BB+b)*HRR + j] = h;
    }
    __syncthreads();
  }
}

// ---------------- runoff = leaky(hs @ fcW^T + fcb), + inflow at node 753 ----------------
__global__ __launch_bounds__(256) void k_runoff(
    const float* __restrict__ hs, const float* __restrict__ fcW,
    const float* __restrict__ fcb, const float* __restrict__ inflow,
    float* __restrict__ runoff, float* __restrict__ lat){
  int p = blockIdx.x;
  int q = p & 3; int tb = p >> 2; int t = tb >> 5; int b = tb & 31;
  int n = q*256 + threadIdx.x;
  __shared__ float hrow[HRR];
  if(threadIdx.x < HRR) hrow[threadIdx.x] = hs[(t*BB+b)*HRR + threadIdx.x];
  __syncthreads();
  const float* wrow = fcW + n*HRR;
  float acc = 0.f;
  #pragma unroll
  for(int k=0;k<HRR;k+=4){
    float4 w = *reinterpret_cast<const float4*>(wrow + k);
    acc = fmaf(w.x, hrow[k+0], acc);
    acc = fmaf(w.y, hrow[k+1], acc);
    acc = fmaf(w.z, hrow[k+2], acc);
    acc = fmaf(w.w, hrow[k+3], acc);
  }
  acc += fcb[n];
  float r = leaky(acc, 0.01f);
  if(n == 753) r += inflow[b*TT + t];
  runoff[(t*BB+b)*NNODE + n] = r;
  lat[(size_t)(b*TT+t)*NNODE + n] = r;
}

// ---------------- CSR by dst (deterministic) ----------------
__global__ __launch_bounds__(1024) void k_csr_off(const int* __restrict__ ei, int* __restrict__ off){
  __shared__ int deg[NNODE];
  __shared__ int scn[NNODE];
  int tid = threadIdx.x;
  deg[tid] = 1;  // self loop
  __syncthreads();
  for(int e=tid; e<EE; e+=1024) atomicAdd(&deg[ei[EE+e]], 1);
  __syncthreads();
  scn[tid] = deg[tid];
  __syncthreads();
  for(int ofs=1; ofs<1024; ofs<<=1){
    int add = (tid>=ofs)? scn[tid-ofs] : 0;
    __syncthreads();
    scn[tid] += add;
    __syncthreads();
  }
  off[tid+1] = scn[tid];
  if(tid==0) off[0] = 0;
}

__global__ __launch_bounds__(1024) void k_csr_fill(const int* __restrict__ ei,
    const int* __restrict__ off, int* __restrict__ adj){
  __shared__ int dstb[EE];
  int tid = threadIdx.x;
  for(int e=tid; e<EE; e+=1024) dstb[e] = ei[EE+e];
  __syncthreads();
  int e = blockIdx.x*1024 + tid;
  int myd = dstb[e];
  int rank = 0;
  for(int ep=0; ep<e; ep++) rank += (dstb[ep]==myd) ? 1 : 0;
  adj[off[myd]+rank] = e;
  if(blockIdx.x==0) adj[off[tid+1]-1] = EE + tid;   // self loop last in bucket
}

// ---------------- GAT1 node prep: (xn0, xn1, runoff_t) -> h1 (24), s1 (8), d1 (8) ----------------
__global__ __launch_bounds__(256) void k_prep1(const float* __restrict__ xn,
    const float* __restrict__ runoff,
    const float* __restrict__ g1W, const float* __restrict__ g1as, const float* __restrict__ g1ad,
    float* __restrict__ h1, float* __restrict__ s1, float* __restrict__ d1, int t){
  int idx = blockIdx.x*256 + threadIdx.x;    // 32768 = B*N
  int b = idx >> 10; int n = idx & 1023;
  float x0 = 0.f, x1 = 0.f;
  if(t > 0){
    x0 = xn[b*TWO_N + 2*n];
    x1 = xn[b*TWO_N + 2*n + 1];
  }
  float x2 = runoff[((size_t)t*BB + b)*NNODE + n];
  float hv[24];
  size_t base = (size_t)b*NNODE + n;
  #pragma unroll
  for(int o=0;o<24;o++){
    hv[o] = x0*g1W[o] + x1*g1W[24+o] + x2*g1W[48+o];
    h1[base*24+o] = hv[o];
  }
  #pragma unroll
  for(int hd=0; hd<NHEAD; hd++){
    float s=0.f, d=0.f;
    #pragma unroll
    for(int c=0;c<3;c++){
      float v = hv[hd*3+c];
      s = fmaf(v, g1as[hd*3+c], s);
      d = fmaf(v, g1ad[hd*3+c], d);
    }
    s1[base*8+hd] = s; d1[base*8+hd] = d;
  }
}

// ---------------- GAT1 edge pass -> att(t), x1 ----------------
__global__ __launch_bounds__(256) void k_gat1e(const int* __restrict__ ei,
    const int* __restrict__ off, const int* __restrict__ adj,
    const float* __restrict__ h1, const float* __restrict__ s1, const float* __restrict__ d1,
    const float* __restrict__ g1b, float* __restrict__ x1out,
    float* __restrict__ att, int t){
  int tid = threadIdx.x;
  int g = tid >> 3; int hd = tid & 7;
  int p = blockIdx.x*32 + g;                 // (b,n)
  int b = p >> 10; int n = p & 1023;
  int o0 = off[n], o1 = off[n+1];
  size_t bbase = (size_t)b*NNODE;
  float dn = d1[(bbase+n)*8+hd];
  float m = -1e30f;
  for(int idx=o0; idx<o1; idx++){
    int eid = adj[idx];
    int s = (eid < EE) ? ei[eid] : n;
    float lg = leaky(s1[(bbase+s)*8+hd] + dn, 0.2f);
    m = fmaxf(m, lg);
  }
  float den = 0.f;
  for(int idx=o0; idx<o1; idx++){
    int eid = adj[idx];
    int s = (eid < EE) ? ei[eid] : n;
    float lg = leaky(s1[(bbase+s)*8+hd] + dn, 0.2f);
    den += expf(lg - m);
  }
  float inv = 1.f/(den + 1e-16f);
  float o_0=0.f, o_1=0.f, o_2=0.f;
  for(int idx=o0; idx<o1; idx++){
    int eid = adj[idx];
    int s = (eid < EE) ? ei[eid] : n;
    float lg = leaky(s1[(bbase+s)*8+hd] + dn, 0.2f);
    float al = expf(lg - m)*inv;
    att[((size_t)(t*BB+b)*NEDGE + eid)*NHEAD + hd] = al;
    const float* hr = h1 + (bbase+s)*24 + hd*3;
    o_0 = fmaf(hr[0], al, o_0);
    o_1 = fmaf(hr[1], al, o_1);
    o_2 = fmaf(hr[2], al, o_2);
  }
  x1out[(bbase+n)*24 + hd*3+0] = leaky(o_0 + g1b[hd*3+0], 0.01f);
  x1out[(bbase+n)*24 + hd*3+1] = leaky(o_1 + g1b[hd*3+1], 0.01f);
  x1out[(bbase+n)*24 + hd*3+2] = leaky(o_2 + g1b[hd*3+2], 0.01f);
}

// ---------------- GAT2 node prep: x1 (24) -> h2 (16), s2 (8), d2 (8) ----------------
__global__ __launch_bounds__(256) void k_prep2(const float* __restrict__ x1,
    const float* __restrict__ g2W, const float* __restrict__ g2as, const float* __restrict__ g2ad,
    float* __restrict__ h2, float* __restrict__ s2, float* __restrict__ d2){
  int idx = blockIdx.x*256 + threadIdx.x;    // 32768
  int b = idx >> 10; int n = idx & 1023;
  size_t base = (size_t)b*NNODE + n;
  float xv[24];
  #pragma unroll
  for(int k=0;k<24;k++) xv[k] = x1[base*24+k];
  #pragma unroll
  for(int hd=0; hd<NHEAD; hd++){
    float h0=0.f, h1v=0.f;
    #pragma unroll
    for(int k=0;k<24;k++){
      h0  = fmaf(xv[k], g2W[k*16+hd*2],   h0);
      h1v = fmaf(xv[k], g2W[k*16+hd*2+1], h1v);
    }
    h2[base*16+hd*2]   = h0;
    h2[base*16+hd*2+1] = h1v;
    s2[base*8+hd] = h0*g2as[hd*2] + h1v*g2as[hd*2+1];
    d2[base*8+hd] = h0*g2ad[hd*2] + h1v*g2ad[hd*2+1];
  }
}

// ---------------- GAT2 edge pass -> xf ----------------
__global__ __launch_bounds__(256) void k_gat2e(const int* __restrict__ ei,
    const int* __restrict__ off, const int* __restrict__ adj,
    const float* __restrict__ h2, const float* __restrict__ s2, const float* __restrict__ d2,
    const float* __restrict__ g2b, float* __restrict__ xf){
  int tid = threadIdx.x;
  int g = tid >> 3; int hd = tid & 7;
  int p = blockIdx.x*32 + g;
  int b = p >> 10; int n = p & 1023;
  __shared__ float outbuf[32][17];
  int o0 = off[n], o1 = off[n+1];
  size_t bbase = (size_t)b*NNODE;
  float dn = d2[(bbase+n)*8+hd];
  float m = -1e30f;
  for(int idx=o0; idx<o1; idx++){
    int eid = adj[idx];
    int s = (eid < EE) ? ei[eid] : n;
    float lg = leaky(s2[(bbase+s)*8+hd] + dn, 0.2f);
    m = fmaxf(m, lg);
  }
  float den = 0.f;
  for(int idx=o0; idx<o1; idx++){
    int eid = adj[idx];
    int s = (eid < EE) ? ei[eid] : n;
    float lg = leaky(s2[(bbase+s)*8+hd] + dn, 0.2f);
    den += expf(lg - m);
  }
  float inv = 1.f/(den + 1e-16f);
  float o_0=0.f, o_1=0.f;
  for(int idx=o0; idx<o1; idx++){
    int eid = adj[idx];
    int s = (eid < EE) ? ei[eid] : n;
    float lg = leaky(s2[(bbase+s)*8+hd] + dn, 0.2f);
    float al = expf(lg - m)*inv;
    const float* hr = h2 + (bbase+s)*16 + hd*2;
    o_0 = fmaf(hr[0], al, o_0);
    o_1 = fmaf(hr[1], al, o_1);
  }
  outbuf[g][hd*2+0] = o_0;
  outbuf[g][hd*2+1] = o_1;
  __syncthreads();
  if(hd < 2){
    float acc = 0.f;
    #pragma unroll
    for(int k=0;k<8;k++) acc += outbuf[g][k*2+hd];
    float v = leaky(acc*0.125f + g2b[hd], 0.01f);
    xf[b*TWO_N + n*2 + hd] = v;
  }
}

// ---------------- cell GEMM: g[b,j] = [xf|hn] . [Wih|Whh][j,:] + biases ----------------
__global__ __launch_bounds__(256) void k_cell_gemm(const float* __restrict__ xf,
    const float* __restrict__ hn, const float* __restrict__ Wih, const float* __restrict__ Whh,
    const float* __restrict__ bih, const float* __restrict__ bhh, float* __restrict__ gout){
  __shared__ float xl[256*33];
  int tid = threadIdx.x;
  int jl = tid >> 5; int b = tid & 31;
  int j = blockIdx.x*8 + jl;
  float acc = 0.f;
  for(int k0=0; k0<KCELL; k0+=256){
    if(k0 < TWO_N){
      for(int i=0;i<32;i++) xl[tid*33+i] = xf[i*TWO_N + k0 + tid];
    } else {
      for(int i=0;i<32;i++) xl[tid*33+i] = hn[i*HLL + (k0-TWO_N) + tid];
    }
    __syncthreads();
    const float* wrow = (k0 < TWO_N) ? (Wih + (size_t)j*TWO_N + k0)
                                     : (Whh + (size_t)j*HLL + (k0-TWO_N));
    #pragma unroll 4
    for(int kk=0; kk<256; kk+=8){
      float4 w0 = *reinterpret_cast<const float4*>(wrow + kk);
      float4 w1 = *reinterpret_cast<const float4*>(wrow + kk + 4);
      const float* xp = &xl[kk*33 + b];
      acc = fmaf(w0.x, xp[0*33], acc);
      acc = fmaf(w0.y, xp[1*33], acc);
      acc = fmaf(w0.z, xp[2*33], acc);
      acc = fmaf(w0.w, xp[3*33], acc);
      acc = fmaf(w1.x, xp[4*33], acc);
      acc = fmaf(w1.y, xp[5*33], acc);
      acc = fmaf(w1.z, xp[6*33], acc);
      acc = fmaf(w1.w, xp[7*33], acc);
    }
    __syncthreads();
  }
  gout[b*TWO_N + j] = acc + bih[j] + bhh[j];
}

// ---------------- gates + LayerNorm ----------------
__global__ __launch_bounds__(512) void k_cell_gate(const float* __restrict__ g,
    float* __restrict__ cn, float* __restrict__ hn,
    const float* __restrict__ lng, const float* __restrict__ lnb){
  int b = blockIdx.x; int u = threadIdx.x;   // 512
  const float* gr = g + b*TWO_N;
  float c = sigmoidf_(gr[HLL+u])*cn[b*HLL+u] + sigmoidf_(gr[u])*tanhf(gr[2*HLL+u]);
  cn[b*HLL+u] = c;
  float h = sigmoidf_(gr[3*HLL+u])*tanhf(c);
  __shared__ float red[HLL];
  __shared__ float red2[HLL];
  red[u] = h; red2[u] = h*h;
  __syncthreads();
  for(int s=256; s>0; s>>=1){
    if(u < s){ red[u] += red[u+s]; red2[u] += red2[u+s]; }
    __syncthreads();
  }
  float mu = red[0] * (1.f/HLL);
  float var = red2[0] * (1.f/HLL) - mu*mu;
  float rstd = rsqrtf(var + 1e-5f);
  hn[b*HLL+u] = (h-mu)*rstd*lng[u] + lnb[u];
}

// ---------------- lin GEMM + softplus -> pred(t), xn ----------------
__global__ __launch_bounds__(256) void k_lin(const float* __restrict__ hn,
    const float* __restrict__ W, const float* __restrict__ bias,
    float* __restrict__ pred, float* __restrict__ xn, int t){
  __shared__ float hl[256*33];
  int tid = threadIdx.x;
  int jl = tid >> 5; int b = tid & 31;
  int j = blockIdx.x*8 + jl;
  float acc = 0.f;
  for(int k0=0; k0<HLL; k0+=256){
    for(int i=0;i<32;i++) hl[tid*33+i] = hn[i*HLL + k0 + tid];
    __syncthreads();
    const float* wrow = W + (size_t)j*HLL + k0;
    #pragma unroll 4
    for(int kk=0; kk<256; kk+=8){
      float4 w0 = *reinterpret_cast<const float4*>(wrow + kk);
      float4 w1 = *reinterpret_cast<const float4*>(wrow + kk + 4);
      const float* xp = &hl[kk*33 + b];
      acc = fmaf(w0.x, xp[0*33], acc);
      acc = fmaf(w0.y, xp[1*33], acc);
      acc = fmaf(w0.z, xp[2*33], acc);
      acc = fmaf(w0.w, xp[3*33], acc);
      acc = fmaf(w1.x, xp[4*33], acc);
      acc = fmaf(w1.y, xp[5*33], acc);
      acc = fmaf(w1.z, xp[6*33], acc);
      acc = fmaf(w1.w, xp[7*33], acc);
    }
    __syncthreads();
  }
  float val = acc + bias[j];
  float sp = fmaxf(val, 0.f) + log1pf(expf(-fabsf(val)));   // softplus, stable
  pred[((size_t)b*TT + t)*TWO_N + j] = sp;
  xn[b*TWO_N + j] = sp;
}

// ---------------- init hn/cn to zero ----------------
__global__ __launch_bounds__(512) void k_init(float* __restrict__ hn, float* __restrict__ cn){
  int idx = blockIdx.x*512 + threadIdx.x;   // 32768
  if(idx < BB*HLL) hn[idx] = 0.f;
  else cn[idx - BB*HLL] = 0.f;
}

extern "C" void kernel_launch(void* const* d_in, const int* in_sizes, int n_in,
                              void* d_out, int out_size, void* d_ws, size_t ws_size,
                              hipStream_t stream){
  const float* rainfall  = (const float*)d_in[0];
  const float* inflow    = (const float*)d_in[1];
  const int*   edge_index= (const int*)  d_in[2];
  const float* lstm_Wih  = (const float*)d_in[3];
  const float* lstm_Whh  = (const float*)d_in[4];
  const float* lstm_bih  = (const float*)d_in[5];
  const float* lstm_bhh  = (const float*)d_in[6];
  const float* fc_W      = (const float*)d_in[7];
  const float* fc_b      = (const float*)d_in[8];
  const float* g1_W      = (const float*)d_in[9];
  const float* g1_as     = (const float*)d_in[10];
  const float* g1_ad     = (const float*)d_in[11];
  const float* g1_b      = (const float*)d_in[12];
  const float* g2_W      = (const float*)d_in[13];
  const float* g2_as     = (const float*)d_in[14];
  const float* g2_ad     = (const float*)d_in[15];
  const float* g2_b      = (const float*)d_in[16];
  const float* cell_Wih  = (const float*)d_in[17];
  const float* cell_Whh  = (const float*)d_in[18];
  const float* cell_bih  = (const float*)d_in[19];
  const float* cell_bhh  = (const float*)d_in[20];
  const float* ln_g      = (const float*)d_in[21];
  const float* ln_b      = (const float*)d_in[22];
  const float* lin_W     = (const float*)d_in[23];
  const float* lin_b     = (const float*)d_in[24];

  // Outputs are FLOAT32 (reference returns f32; out_npz size matches 90.2M f32)
  float* out  = (float*)d_out;
  float* pred = out;                       // (B,T,2N) = 4194304
  float* lat  = out + (size_t)4194304;     // (B,T,N,1) = 2097152
  float* att  = out + (size_t)6291456;     // (T,B,5120,8) = 83886080

  // ws layout (floats unless noted)
  float* ws = (float*)d_ws;
  float* hs     = ws;                        // 131072
  float* runoff = hs + 131072;               // 2097152
  float* h1     = runoff + 2097152;          // 786432
  float* s1     = h1 + 786432;               // 262144
  float* d1     = s1 + 262144;               // 262144
  float* x1b    = d1 + 262144;               // 786432
  float* h2     = x1b + 786432;              // 524288
  float* s2     = h2 + 524288;               // 262144
  float* d2     = s2 + 262144;               // 262144
  float* xnb    = d2 + 262144;               // 65536
  float* xfb    = xnb + 65536;               // 65536
  float* gbuf   = xfb + 65536;               // 65536
  float* hn     = gbuf + 65536;              // 16384
  float* cn     = hn + 16384;                // 16384
  int*   off    = (int*)(cn + 16384);        // 1025 (pad to 1032)
  int*   adj    = off + 1032;                // 5120
  if(ws_size < 22437920ull) return;          // diagnostic: zero output

  k_init<<<64, 512, 0, stream>>>(hn, cn);
  k_csr_off<<<1, 1024, 0, stream>>>(edge_index, off);
  k_csr_fill<<<4, 1024, 0, stream>>>(edge_index, off, adj);
  k_lstm<<<BB, 256, 0, stream>>>(rainfall, lstm_Wih, lstm_Whh, lstm_bih, lstm_bhh, hs);
  k_runoff<<<TT*BB*4, 256, 0, stream>>>(hs, fc_W, fc_b, inflow, runoff, lat);

  for(int t=0; t<TT; t++){
    k_prep1<<<128, 256, 0, stream>>>(xnb, runoff, g1_W, g1_as, g1_ad, h1, s1, d1, t);
    k_gat1e<<<1024, 256, 0, stream>>>(edge_index, off, adj, h1, s1, d1,
        g1_b, x1b, att, t);
    k_prep2<<<128, 256, 0, stream>>>(x1b, g2_W, g2_as, g2_ad, h2, s2, d2);
    k_gat2e<<<1024, 256, 0, stream>>>(edge_index, off, adj, h2, s2, d2, g2_b, xfb);
    k_cell_gemm<<<256, 256, 0, stream>>>(xfb, hn, cell_Wih, cell_Whh, cell_bih, cell_bhh, gbuf);
    k_cell_gate<<<BB, 512, 0, stream>>>(gbuf, cn, hn, ln_g, ln_b);
    k_lin<<<256, 256, 0, stream>>>(hn, lin_W, lin_b, pred, xnb, t);
  }
}

// Round 6
// 5196.470 us; speedup vs baseline: 1.6605x; 1.6605x over previous
//
#include <hip/hip_runtime.h>
#include <hip/hip_bf16.h>

#define BB 32
#define TT 64
#define NNODE 1024
#define EE 4096
#define NEDGE 5120        // EE + NNODE self loops
#define NHEAD 8
#define HLL 512
#define HRR 64
#define TWO_N 2048
#define KCELL 2560        // 2048 (xf) + 512 (hn)

__device__ __forceinline__ float sigmoidf_(float x){ return 1.f/(1.f+expf(-x)); }
__device__ __forceinline__ float leaky(float x, float s){ return x>0.f? x : s*x; }

// ---------------- LSTM over T steps, one block per batch ----------------
__global__ __launch_bounds__(256) void k_lstm(
    const float* __restrict__ rain, const float* __restrict__ Wih,
    const float* __restrict__ Whh, const float* __restrict__ bih,
    const float* __restrict__ bhh, float* __restrict__ hs){
  int b = blockIdx.x;
  int j = threadIdx.x;          // gate row 0..255
  __shared__ float h_lds[HRR];
  __shared__ float g_lds[4*HRR];
  float wh[HRR];
  #pragma unroll
  for(int k=0;k<HRR;k++) wh[k] = Whh[j*HRR+k];
  float wi = Wih[j];
  float bias = bih[j] + bhh[j];
  float c = 0.f;
  if(j < HRR) h_lds[j] = 0.f;
  __syncthreads();
  for(int t=0;t<TT;t++){
    float x = rain[b*TT+t];
    float g = fmaf(wi, x, bias);
    #pragma unroll
    for(int k=0;k<HRR;k++) g = fmaf(wh[k], h_lds[k], g);
    g_lds[j] = g;
    __syncthreads();
    if(j < HRR){
      c = sigmoidf_(g_lds[HRR+j])*c + sigmoidf_(g_lds[j])*tanhf(g_lds[2*HRR+j]);
      float h = sigmoidf_(g_lds[3*HRR+j])*tanhf(c);
      h_lds[j] = h;
      hs[(t*BB+b)*HRR + j] = h;
    }
    __syncthreads();
  }
}

// ---------------- runoff = leaky(hs @ fcW^T + fcb), + inflow at node 753 ----------------
__global__ __launch_bounds__(256) void k_runoff(
    const float* __restrict__ hs, const float* __restrict__ fcW,
    const float* __restrict__ fcb, const float* __restrict__ inflow,
    float* __restrict__ runoff, float* __restrict__ lat){
  int p = blockIdx.x;
  int q = p & 3; int tb = p >> 2; int t = tb >> 5; int b = tb & 31;
  int n = q*256 + threadIdx.x;
  __shared__ float hrow[HRR];
  if(threadIdx.x < HRR) hrow[threadIdx.x] = hs[(t*BB+b)*HRR + threadIdx.x];
  __syncthreads();
  const float* wrow = fcW + n*HRR;
  float a0=0.f,a1=0.f,a2=0.f,a3=0.f;
  #pragma unroll
  for(int k=0;k<HRR;k+=4){
    float4 w = *reinterpret_cast<const float4*>(wrow + k);
    a0 = fmaf(w.x, hrow[k+0], a0);
    a1 = fmaf(w.y, hrow[k+1], a1);
    a2 = fmaf(w.z, hrow[k+2], a2);
    a3 = fmaf(w.w, hrow[k+3], a3);
  }
  float acc = (a0+a1)+(a2+a3) + fcb[n];
  float r = leaky(acc, 0.01f);
  if(n == 753) r += inflow[b*TT + t];
  runoff[(t*BB+b)*NNODE + n] = r;
  lat[(size_t)(b*TT+t)*NNODE + n] = r;
}

// ---------------- CSR by dst (deterministic), packed (src<<13 | eid) ----------------
__global__ __launch_bounds__(1024) void k_csr_off(const int* __restrict__ ei, int* __restrict__ off){
  __shared__ int deg[NNODE];
  __shared__ int scn[NNODE];
  int tid = threadIdx.x;
  deg[tid] = 1;  // self loop
  __syncthreads();
  for(int e=tid; e<EE; e+=1024) atomicAdd(&deg[ei[EE+e]], 1);
  __syncthreads();
  scn[tid] = deg[tid];
  __syncthreads();
  for(int ofs=1; ofs<1024; ofs<<=1){
    int add = (tid>=ofs)? scn[tid-ofs] : 0;
    __syncthreads();
    scn[tid] += add;
    __syncthreads();
  }
  off[tid+1] = scn[tid];
  if(tid==0) off[0] = 0;
}

__global__ __launch_bounds__(1024) void k_csr_fill(const int* __restrict__ ei,
    const int* __restrict__ off, int* __restrict__ adjp){
  __shared__ int dstb[EE];
  int tid = threadIdx.x;
  for(int e=tid; e<EE; e+=1024) dstb[e] = ei[EE+e];
  __syncthreads();
  int e = blockIdx.x*1024 + tid;
  int myd = dstb[e];
  int rank = 0;
  for(int ep=0; ep<e; ep++) rank += (dstb[ep]==myd) ? 1 : 0;
  adjp[off[myd]+rank] = (ei[e] << 13) | e;                 // real edge: src, eid
  if(blockIdx.x==0) adjp[off[tid+1]-1] = (tid << 13) | (EE + tid);  // self loop last
}

// ---------------- GAT1 node prep for t=0 ----------------
__global__ __launch_bounds__(256) void k_prep0(const float* __restrict__ runoff,
    const float* __restrict__ g1W, const float* __restrict__ g1as, const float* __restrict__ g1ad,
    float* __restrict__ h1, float* __restrict__ s1, float* __restrict__ d1){
  int idx = blockIdx.x*256 + threadIdx.x;    // 32768 = B*N
  int b = idx >> 10; int n = idx & 1023;
  float x2 = runoff[b*NNODE + n];            // t=0
  float hv[24];
  size_t base = (size_t)b*NNODE + n;
  #pragma unroll
  for(int o=0;o<24;o++){
    hv[o] = x2*g1W[48+o];
    h1[base*24+o] = hv[o];
  }
  #pragma unroll
  for(int hd=0; hd<NHEAD; hd++){
    float s=0.f, d=0.f;
    #pragma unroll
    for(int c=0;c<3;c++){
      float v = hv[hd*3+c];
      s = fmaf(v, g1as[hd*3+c], s);
      d = fmaf(v, g1ad[hd*3+c], d);
    }
    s1[base*8+hd] = s; d1[base*8+hd] = d;
  }
}

// ---------------- GAT1 edge pass (2-pass online softmax, LDS s-table) + GAT2 prep ----------------
__global__ __launch_bounds__(256) void k_gat1f(
    const int* __restrict__ adjp, const int* __restrict__ off,
    const float* __restrict__ h1, const float* __restrict__ s1, const float* __restrict__ d1,
    const float* __restrict__ g1b, const float* __restrict__ g2W,
    const float* __restrict__ g2as, const float* __restrict__ g2ad,
    float* __restrict__ h2, float* __restrict__ s2, float* __restrict__ d2,
    float* __restrict__ att, int t){
  int tid = threadIdx.x;
  int g = tid >> 3; int hd = tid & 7;
  int p = blockIdx.x*32 + g;                 // (b,n); all groups in a block share b
  int b = p >> 10; int n = p & 1023;
  __shared__ float ss[NNODE*NHEAD];          // 32 KB: s1 for this b
  __shared__ float x1buf[32][25];
  size_t bbase = (size_t)b*NNODE;
  for(int i=tid; i<NNODE*NHEAD; i+=256) ss[i] = s1[bbase*8 + i];
  __syncthreads();
  int o0 = off[n], o1 = off[n+1];
  float dn = d1[(bbase+n)*8+hd];
  float m = -1e30f, den = 0.f;
  for(int idx=o0; idx<o1; idx++){
    int pk = adjp[idx]; int s = pk >> 13;
    float lg = leaky(ss[s*8+hd] + dn, 0.2f);
    if(lg > m){ den *= expf(m - lg); m = lg; }
    den += expf(lg - m);
  }
  float inv = 1.f/(den + 1e-16f);
  float o_0=0.f, o_1=0.f, o_2=0.f;
  for(int idx=o0; idx<o1; idx++){
    int pk = adjp[idx]; int s = pk >> 13; int eid = pk & 8191;
    float lg = leaky(ss[s*8+hd] + dn, 0.2f);
    float al = expf(lg - m)*inv;
    att[((size_t)(t*BB+b)*NEDGE + eid)*NHEAD + hd] = al;
    const float* hr = h1 + (bbase+s)*24 + hd*3;
    o_0 = fmaf(hr[0], al, o_0);
    o_1 = fmaf(hr[1], al, o_1);
    o_2 = fmaf(hr[2], al, o_2);
  }
  x1buf[g][hd*3+0] = leaky(o_0 + g1b[hd*3+0], 0.01f);
  x1buf[g][hd*3+1] = leaky(o_1 + g1b[hd*3+1], 0.01f);
  x1buf[g][hd*3+2] = leaky(o_2 + g1b[hd*3+2], 0.01f);
  __syncthreads();
  // GAT2 node prep for own node: h2 (16), s2/d2 (8)
  float h2v0=0.f, h2v1=0.f;
  int oA = hd*2, oB = hd*2+1;
  #pragma unroll
  for(int k=0;k<24;k++){
    float xv = x1buf[g][k];
    h2v0 = fmaf(xv, g2W[k*16+oA], h2v0);
    h2v1 = fmaf(xv, g2W[k*16+oB], h2v1);
  }
  h2[(bbase+n)*16+oA] = h2v0;
  h2[(bbase+n)*16+oB] = h2v1;
  s2[(bbase+n)*8+hd] = h2v0*g2as[oA] + h2v1*g2as[oB];
  d2[(bbase+n)*8+hd] = h2v0*g2ad[oA] + h2v1*g2ad[oB];
}

// ---------------- GAT2 edge pass (2-pass online softmax, LDS s-table) -> xf ----------------
__global__ __launch_bounds__(256) void k_gat2f(
    const int* __restrict__ adjp, const int* __restrict__ off,
    const float* __restrict__ h2, const float* __restrict__ s2, const float* __restrict__ d2,
    const float* __restrict__ g2b, float* __restrict__ xf){
  int tid = threadIdx.x;
  int g = tid >> 3; int hd = tid & 7;
  int p = blockIdx.x*32 + g;
  int b = p >> 10; int n = p & 1023;
  __shared__ float ss[NNODE*NHEAD];          // 32 KB: s2 for this b
  __shared__ float outbuf[32][17];
  size_t bbase = (size_t)b*NNODE;
  for(int i=tid; i<NNODE*NHEAD; i+=256) ss[i] = s2[bbase*8 + i];
  __syncthreads();
  int o0 = off[n], o1 = off[n+1];
  float dn = d2[(bbase+n)*8+hd];
  float m = -1e30f, den = 0.f;
  for(int idx=o0; idx<o1; idx++){
    int pk = adjp[idx]; int s = pk >> 13;
    float lg = leaky(ss[s*8+hd] + dn, 0.2f);
    if(lg > m){ den *= expf(m - lg); m = lg; }
    den += expf(lg - m);
  }
  float inv = 1.f/(den + 1e-16f);
  float o_0=0.f, o_1=0.f;
  for(int idx=o0; idx<o1; idx++){
    int pk = adjp[idx]; int s = pk >> 13;
    float lg = leaky(ss[s*8+hd] + dn, 0.2f);
    float al = expf(lg - m)*inv;
    const float* hr = h2 + (bbase+s)*16 + hd*2;
    o_0 = fmaf(hr[0], al, o_0);
    o_1 = fmaf(hr[1], al, o_1);
  }
  outbuf[g][hd*2+0] = o_0;
  outbuf[g][hd*2+1] = o_1;
  __syncthreads();
  if(hd < 2){
    float acc = 0.f;
    #pragma unroll
    for(int k=0;k<8;k++) acc += outbuf[g][k*2+hd];
    float v = leaky(acc*0.125f + g2b[hd], 0.01f);
    xf[b*TWO_N + n*2 + hd] = v;
  }
}

// ---------------- cell GEMM split-K: halves write g0/g1 partials ----------------
__global__ __launch_bounds__(256) void k_cell_gemm(const float* __restrict__ xf,
    const float* __restrict__ hn, const float* __restrict__ Wih, const float* __restrict__ Whh,
    float* __restrict__ g0, float* __restrict__ g1){
  __shared__ float xl[256*33];
  int bid = blockIdx.x;
  int half = bid >> 8; int jb = bid & 255;
  int tid = threadIdx.x;
  int jl = tid >> 5; int b = tid & 31;
  int j = jb*8 + jl;
  float a0=0.f,a1=0.f,a2=0.f,a3=0.f;
  int kbeg = half*1280, kend = kbeg + 1280;
  for(int k0=kbeg; k0<kend; k0+=256){
    if(k0 < TWO_N){
      for(int i=0;i<32;i++) xl[tid*33+i] = xf[i*TWO_N + k0 + tid];
    } else {
      for(int i=0;i<32;i++) xl[tid*33+i] = hn[i*HLL + (k0-TWO_N) + tid];
    }
    __syncthreads();
    const float* wrow = (k0 < TWO_N) ? (Wih + (size_t)j*TWO_N + k0)
                                     : (Whh + (size_t)j*HLL + (k0-TWO_N));
    #pragma unroll 4
    for(int kk=0; kk<256; kk+=8){
      float4 w0 = *reinterpret_cast<const float4*>(wrow + kk);
      float4 w1 = *reinterpret_cast<const float4*>(wrow + kk + 4);
      const float* xp = &xl[kk*33 + b];
      a0 = fmaf(w0.x, xp[0*33], a0);
      a1 = fmaf(w0.y, xp[1*33], a1);
      a2 = fmaf(w0.z, xp[2*33], a2);
      a3 = fmaf(w0.w, xp[3*33], a3);
      a0 = fmaf(w1.x, xp[4*33], a0);
      a1 = fmaf(w1.y, xp[5*33], a1);
      a2 = fmaf(w1.z, xp[6*33], a2);
      a3 = fmaf(w1.w, xp[7*33], a3);
    }
    __syncthreads();
  }
  float* dst = half ? g1 : g0;
  dst[b*TWO_N + j] = (a0+a1)+(a2+a3);
}

// ---------------- gates (sum partials + biases) + LayerNorm ----------------
__global__ __launch_bounds__(512) void k_cell_gate(const float* __restrict__ g0,
    const float* __restrict__ g1,
    const float* __restrict__ bih, const float* __restrict__ bhh,
    float* __restrict__ cn, float* __restrict__ hn,
    const float* __restrict__ lng, const float* __restrict__ lnb){
  int b = blockIdx.x; int u = threadIdx.x;   // 512
  const float* r0 = g0 + b*TWO_N;
  const float* r1 = g1 + b*TWO_N;
  float gi = r0[u]         + r1[u]         + bih[u]         + bhh[u];
  float gf = r0[HLL+u]     + r1[HLL+u]     + bih[HLL+u]     + bhh[HLL+u];
  float gg = r0[2*HLL+u]   + r1[2*HLL+u]   + bih[2*HLL+u]   + bhh[2*HLL+u];
  float go = r0[3*HLL+u]   + r1[3*HLL+u]   + bih[3*HLL+u]   + bhh[3*HLL+u];
  float c = sigmoidf_(gf)*cn[b*HLL+u] + sigmoidf_(gi)*tanhf(gg);
  cn[b*HLL+u] = c;
  float h = sigmoidf_(go)*tanhf(c);
  __shared__ float red[HLL];
  __shared__ float red2[HLL];
  red[u] = h; red2[u] = h*h;
  __syncthreads();
  for(int s=256; s>0; s>>=1){
    if(u < s){ red[u] += red[u+s]; red2[u] += red2[u+s]; }
    __syncthreads();
  }
  float mu = red[0] * (1.f/HLL);
  float var = red2[0] * (1.f/HLL) - mu*mu;
  float rstd = rsqrtf(var + 1e-5f);
  hn[b*HLL+u] = (h-mu)*rstd*lng[u] + lnb[u];
}

// ---------------- lin GEMM + softplus -> pred(t) + fused next-step GAT1 prep ----------------
__global__ __launch_bounds__(256) void k_lin(const float* __restrict__ hn,
    const float* __restrict__ W, const float* __restrict__ bias,
    const float* __restrict__ runoff, float* __restrict__ pred,
    float* __restrict__ h1, float* __restrict__ s1, float* __restrict__ d1,
    const float* __restrict__ g1W, const float* __restrict__ g1as, const float* __restrict__ g1ad,
    int t){
  __shared__ float hl[256*33];
  int tid = threadIdx.x;
  int jl = tid >> 5; int b = tid & 31;
  int j = blockIdx.x*8 + jl;
  float a0=0.f,a1=0.f,a2=0.f,a3=0.f;
  for(int k0=0; k0<HLL; k0+=256){
    for(int i=0;i<32;i++) hl[tid*33+i] = hn[i*HLL + k0 + tid];
    __syncthreads();
    const float* wrow = W + (size_t)j*HLL + k0;
    #pragma unroll 4
    for(int kk=0; kk<256; kk+=8){
      float4 w0 = *reinterpret_cast<const float4*>(wrow + kk);
      float4 w1 = *reinterpret_cast<const float4*>(wrow + kk + 4);
      const float* xp = &hl[kk*33 + b];
      a0 = fmaf(w0.x, xp[0*33], a0);
      a1 = fmaf(w0.y, xp[1*33], a1);
      a2 = fmaf(w0.z, xp[2*33], a2);
      a3 = fmaf(w0.w, xp[3*33], a3);
      a0 = fmaf(w1.x, xp[4*33], a0);
      a1 = fmaf(w1.y, xp[5*33], a1);
      a2 = fmaf(w1.z, xp[6*33], a2);
      a3 = fmaf(w1.w, xp[7*33], a3);
    }
    __syncthreads();
  }
  float val = (a0+a1)+(a2+a3) + bias[j];
  float sp = fmaxf(val, 0.f) + log1pf(expf(-fabsf(val)));   // softplus, stable
  pred[((size_t)b*TT + t)*TWO_N + j] = sp;
  if(t+1 < TT){
    float partner = __shfl_xor(sp, 32);   // pairs jl<->jl^1 within wave64, same b
    if((jl & 1) == 0){
      int n = j >> 1;
      float x2 = runoff[(size_t)(t+1)*BB*NNODE + b*NNODE + n];
      float hv[24];
      size_t base = (size_t)b*NNODE + n;
      #pragma unroll
      for(int o=0;o<24;o++){
        hv[o] = sp*g1W[o] + partner*g1W[24+o] + x2*g1W[48+o];
        h1[base*24+o] = hv[o];
      }
      #pragma unroll
      for(int hd=0; hd<NHEAD; hd++){
        float s=0.f, d=0.f;
        #pragma unroll
        for(int c=0;c<3;c++){
          float v = hv[hd*3+c];
          s = fmaf(v, g1as[hd*3+c], s);
          d = fmaf(v, g1ad[hd*3+c], d);
        }
        s1[base*8+hd] = s; d1[base*8+hd] = d;
      }
    }
  }
}

// ---------------- init hn/cn to zero ----------------
__global__ __launch_bounds__(512) void k_init(float* __restrict__ hn, float* __restrict__ cn){
  int idx = blockIdx.x*512 + threadIdx.x;   // 32768
  if(idx < BB*HLL) hn[idx] = 0.f;
  else cn[idx - BB*HLL] = 0.f;
}

extern "C" void kernel_launch(void* const* d_in, const int* in_sizes, int n_in,
                              void* d_out, int out_size, void* d_ws, size_t ws_size,
                              hipStream_t stream){
  const float* rainfall  = (const float*)d_in[0];
  const float* inflow    = (const float*)d_in[1];
  const int*   edge_index= (const int*)  d_in[2];
  const float* lstm_Wih  = (const float*)d_in[3];
  const float* lstm_Whh  = (const float*)d_in[4];
  const float* lstm_bih  = (const float*)d_in[5];
  const float* lstm_bhh  = (const float*)d_in[6];
  const float* fc_W      = (const float*)d_in[7];
  const float* fc_b      = (const float*)d_in[8];
  const float* g1_W      = (const float*)d_in[9];
  const float* g1_as     = (const float*)d_in[10];
  const float* g1_ad     = (const float*)d_in[11];
  const float* g1_b      = (const float*)d_in[12];
  const float* g2_W      = (const float*)d_in[13];
  const float* g2_as     = (const float*)d_in[14];
  const float* g2_ad     = (const float*)d_in[15];
  const float* g2_b      = (const float*)d_in[16];
  const float* cell_Wih  = (const float*)d_in[17];
  const float* cell_Whh  = (const float*)d_in[18];
  const float* cell_bih  = (const float*)d_in[19];
  const float* cell_bhh  = (const float*)d_in[20];
  const float* ln_g      = (const float*)d_in[21];
  const float* ln_b      = (const float*)d_in[22];
  const float* lin_W     = (const float*)d_in[23];
  const float* lin_b     = (const float*)d_in[24];

  float* out  = (float*)d_out;
  float* pred = out;                       // (B,T,2N) = 4194304
  float* lat  = out + (size_t)4194304;     // (B,T,N,1) = 2097152
  float* att  = out + (size_t)6291456;     // (T,B,5120,8)

  float* ws = (float*)d_ws;
  float* hs     = ws;                        // 131072
  float* runoff = hs + 131072;               // 2097152
  float* h1     = runoff + 2097152;          // 786432
  float* s1     = h1 + 786432;               // 262144
  float* d1     = s1 + 262144;               // 262144
  float* h2     = d1 + 262144;               // 524288
  float* s2     = h2 + 524288;               // 262144
  float* d2     = s2 + 262144;               // 262144
  float* xfb    = d2 + 262144;               // 65536
  float* g0buf  = xfb + 65536;               // 65536
  float* g1buf  = g0buf + 65536;             // 65536
  float* hn     = g1buf + 65536;             // 16384
  float* cn     = hn + 16384;                // 16384
  int*   off    = (int*)(cn + 16384);        // 1025 (pad 1032)
  int*   adjp   = off + 1032;                // 5120
  if(ws_size < 19292192ull) return;          // diagnostic: zero output

  k_init<<<64, 512, 0, stream>>>(hn, cn);
  k_csr_off<<<1, 1024, 0, stream>>>(edge_index, off);
  k_csr_fill<<<4, 1024, 0, stream>>>(edge_index, off, adjp);
  k_lstm<<<BB, 256, 0, stream>>>(rainfall, lstm_Wih, lstm_Whh, lstm_bih, lstm_bhh, hs);
  k_runoff<<<TT*BB*4, 256, 0, stream>>>(hs, fc_W, fc_b, inflow, runoff, lat);
  k_prep0<<<128, 256, 0, stream>>>(runoff, g1_W, g1_as, g1_ad, h1, s1, d1);

  for(int t=0; t<TT; t++){
    k_gat1f<<<1024, 256, 0, stream>>>(adjp, off, h1, s1, d1,
        g1_b, g2_W, g2_as, g2_ad, h2, s2, d2, att, t);
    k_gat2f<<<1024, 256, 0, stream>>>(adjp, off, h2, s2, d2, g2_b, xfb);
    k_cell_gemm<<<512, 256, 0, stream>>>(xfb, hn, cell_Wih, cell_Whh, g0buf, g1buf);
    k_cell_gate<<<BB, 512, 0, stream>>>(g0buf, g1buf, cell_bih, cell_bhh, cn, hn, ln_g, ln_b);
    k_lin<<<256, 256, 0, stream>>>(hn, lin_W, lin_b, runoff, pred,
        h1, s1, d1, g1_W, g1_as, g1_ad, t);
  }
}